// Round 1
// baseline (1046.346 us; speedup 1.0000x reference)
//
#include <hip/hip_runtime.h>
#include <hip/hip_bf16.h>

#define DIMC 768
#define NSEQ 2048
#define NB 2
#define NH 12
#define HD 64
#define EPSLN 1e-5f

// ---------------------------------------------------------------------------
// GEMM: C[M=4096][768] = A[M][768] @ W^T (+bias) (+C if ACC)
// W rows have stride ldw (768 for square weights, 1536 for gate_w halves).
// 64x64 tile per 256-thread block, 16-wide K tiles, float4 LDS reads.
// ---------------------------------------------------------------------------
template<bool ACC>
__global__ __launch_bounds__(256)
void gemm_bias_kernel(const float* __restrict__ A,
                      const float* __restrict__ W,
                      const float* __restrict__ bias,
                      float* __restrict__ C,
                      int ldw)
{
    __shared__ float As[16][68];   // pad 68: store addr 68*lk + r -> 2-way (free)
    __shared__ float Bs[16][68];
    const int tx = threadIdx.x & 15;
    const int ty = threadIdx.x >> 4;
    const int m0 = blockIdx.x * 64;
    const int n0 = blockIdx.y * 64;

    float acc[4][4] = {};

    const int lk = threadIdx.x & 15;   // k offset within tile
    const int lr = threadIdx.x >> 4;   // row base 0..15

    for (int k0 = 0; k0 < DIMC; k0 += 16) {
        #pragma unroll
        for (int rr = 0; rr < 64; rr += 16) {
            As[lk][lr + rr] = A[(size_t)(m0 + lr + rr) * DIMC + k0 + lk];
            Bs[lk][lr + rr] = W[(size_t)(n0 + lr + rr) * ldw + k0 + lk];
        }
        __syncthreads();
        #pragma unroll
        for (int kk = 0; kk < 16; ++kk) {
            float4 a = *(const float4*)&As[kk][ty * 4];  // broadcast across tx
            float4 b = *(const float4*)&Bs[kk][tx * 4];  // 2-way (free)
            float av[4] = {a.x, a.y, a.z, a.w};
            float bv[4] = {b.x, b.y, b.z, b.w};
            #pragma unroll
            for (int i = 0; i < 4; ++i)
                #pragma unroll
                for (int j = 0; j < 4; ++j)
                    acc[i][j] += av[i] * bv[j];
        }
        __syncthreads();
    }

    #pragma unroll
    for (int i = 0; i < 4; ++i) {
        const size_t row = (size_t)(m0 + ty * 4 + i) * DIMC + n0 + tx * 4;
        float4 bv = bias ? *(const float4*)&bias[n0 + tx * 4]
                         : make_float4(0.f, 0.f, 0.f, 0.f);
        float4 cv = make_float4(acc[i][0] + bv.x, acc[i][1] + bv.y,
                                acc[i][2] + bv.z, acc[i][3] + bv.w);
        if (ACC) {
            float4 old = *(const float4*)&C[row];
            cv.x += old.x; cv.y += old.y; cv.z += old.z; cv.w += old.w;
        }
        *(float4*)&C[row] = cv;
    }
}

// ---------------------------------------------------------------------------
// Row-wise LayerNorm, in place. MODE 1 additionally applies y*0.125 + pos
// (folds the attention scale and positional term into K).
// One 256-thread block per row of 768.
// ---------------------------------------------------------------------------
template<int MODE>
__global__ __launch_bounds__(256)
void ln_rows_kernel(float* __restrict__ Z,
                    const float* __restrict__ w,
                    const float* __restrict__ b,
                    const float* __restrict__ pos)
{
    const int row = blockIdx.x;
    const int n = row & (NSEQ - 1);
    float x[3];
    float s = 0.f, q = 0.f;
    #pragma unroll
    for (int u = 0; u < 3; ++u) {
        const int j = threadIdx.x + u * 256;
        x[u] = Z[(size_t)row * DIMC + j];
        s += x[u];
        q += x[u] * x[u];
    }
    #pragma unroll
    for (int off = 32; off > 0; off >>= 1) {
        s += __shfl_down(s, off);
        q += __shfl_down(q, off);
    }
    __shared__ float ls[8];
    const int wid = threadIdx.x >> 6;
    if ((threadIdx.x & 63) == 0) { ls[wid] = s; ls[4 + wid] = q; }
    __syncthreads();
    if (threadIdx.x == 0) {
        ls[0] = ls[0] + ls[1] + ls[2] + ls[3];
        ls[4] = ls[4] + ls[5] + ls[6] + ls[7];
    }
    __syncthreads();
    const float mu  = ls[0] * (1.f / DIMC);
    const float var = ls[4] * (1.f / DIMC) - mu * mu;
    const float rs  = rsqrtf(var + EPSLN);
    #pragma unroll
    for (int u = 0; u < 3; ++u) {
        const int j = threadIdx.x + u * 256;
        float y = (x[u] - mu) * rs * w[j] + b[j];
        if (MODE == 1) y = y * 0.125f + pos[(size_t)n * DIMC + j];
        Z[(size_t)row * DIMC + j] = y;
    }
}

// ---------------------------------------------------------------------------
// Flash-style attention. K already holds scale*LN(k)+pos, so S = Q@K^T needs
// no extra scale/bias. Grid: (B*H, N/64). 64 q-rows per block, 256 threads.
// LDS strides are 64: every access is either broadcast or a full 64-word
// spread -> no bank conflicts. Total LDS = 64 KiB.
// ---------------------------------------------------------------------------
__global__ __launch_bounds__(256)
void attn_kernel(const float* __restrict__ Q,
                 const float* __restrict__ K,
                 const float* __restrict__ V,
                 float* __restrict__ O)
{
    __shared__ float Qs [64][64];
    __shared__ float KsT[64][64];   // transposed: KsT[d][m]
    __shared__ float Vs [64][64];
    __shared__ float Ps [64][64];

    const int bh = blockIdx.x;              // 0..23
    const int b  = bh / NH, h = bh % NH;
    const int n0 = blockIdx.y * 64;

    const int tx = threadIdx.x & 15;
    const int ty = threadIdx.x >> 4;

    const size_t base = (size_t)b * NSEQ * DIMC + h * HD;

    {   // load Q tile (coalesced, 256B per row)
        const int d4 = threadIdx.x & 15;
        const int r0 = threadIdx.x >> 4;
        #pragma unroll
        for (int rr = 0; rr < 64; rr += 16) {
            float4 v = *(const float4*)&Q[base + (size_t)(n0 + r0 + rr) * DIMC + d4 * 4];
            *(float4*)&Qs[r0 + rr][d4 * 4] = v;
        }
    }

    float o[4][4] = {};
    float mrow[4] = {-1e30f, -1e30f, -1e30f, -1e30f};
    float lrow[4] = {};

    for (int m0 = 0; m0 < NSEQ; m0 += 64) {
        __syncthreads();  // previous iteration done with KsT/Vs/Ps
        {   // load K tile transposed
            const int mi = threadIdx.x & 63;
            const int dg = threadIdx.x >> 6;   // 0..3
            #pragma unroll
            for (int dd = 0; dd < 4; ++dd) {
                const int d = dg * 16 + dd * 4;
                float4 v = *(const float4*)&K[base + (size_t)(m0 + mi) * DIMC + d];
                KsT[d + 0][mi] = v.x;
                KsT[d + 1][mi] = v.y;
                KsT[d + 2][mi] = v.z;
                KsT[d + 3][mi] = v.w;
            }
        }
        {   // load V tile (row-major)
            const int d4 = threadIdx.x & 15;
            const int r0 = threadIdx.x >> 4;
            #pragma unroll
            for (int rr = 0; rr < 64; rr += 16) {
                float4 v = *(const float4*)&V[base + (size_t)(m0 + r0 + rr) * DIMC + d4 * 4];
                *(float4*)&Vs[r0 + rr][d4 * 4] = v;
            }
        }
        __syncthreads();

        // S tile: rows ty*4+i, cols tx*4+j
        float sv[4][4] = {};
        #pragma unroll 8
        for (int d = 0; d < 64; ++d) {
            float4 kb = *(const float4*)&KsT[d][tx * 4];
            float kv[4] = {kb.x, kb.y, kb.z, kb.w};
            #pragma unroll
            for (int i = 0; i < 4; ++i) {
                const float qa = Qs[ty * 4 + i][d];
                #pragma unroll
                for (int j = 0; j < 4; ++j)
                    sv[i][j] += qa * kv[j];
            }
        }

        // online softmax (row shared by the 16 lanes with equal ty)
        #pragma unroll
        for (int i = 0; i < 4; ++i) {
            float mx = fmaxf(fmaxf(sv[i][0], sv[i][1]), fmaxf(sv[i][2], sv[i][3]));
            #pragma unroll
            for (int off = 1; off < 16; off <<= 1)
                mx = fmaxf(mx, __shfl_xor(mx, off));
            const float mnew = fmaxf(mrow[i], mx);
            const float corr = __expf(mrow[i] - mnew);
            float ps = 0.f;
            #pragma unroll
            for (int j = 0; j < 4; ++j) {
                const float p = __expf(sv[i][j] - mnew);
                sv[i][j] = p;
                ps += p;
            }
            #pragma unroll
            for (int off = 1; off < 16; off <<= 1)
                ps += __shfl_xor(ps, off);
            lrow[i] = lrow[i] * corr + ps;
            mrow[i] = mnew;
            #pragma unroll
            for (int dj = 0; dj < 4; ++dj) o[i][dj] *= corr;
            *(float4*)&Ps[ty * 4 + i][tx * 4] =
                make_float4(sv[i][0], sv[i][1], sv[i][2], sv[i][3]);
        }
        __syncthreads();

        // O += P @ V   (thread owns rows ty*4+i, d-cols tx*4+dj)
        #pragma unroll 8
        for (int mm = 0; mm < 64; ++mm) {
            float4 vb = *(const float4*)&Vs[mm][tx * 4];
            float vv[4] = {vb.x, vb.y, vb.z, vb.w};
            #pragma unroll
            for (int i = 0; i < 4; ++i) {
                const float pa = Ps[ty * 4 + i][mm];
                #pragma unroll
                for (int dj = 0; dj < 4; ++dj)
                    o[i][dj] += pa * vv[dj];
            }
        }
    }

    #pragma unroll
    for (int i = 0; i < 4; ++i) {
        const float inv = 1.f / lrow[i];
        float4 v = make_float4(o[i][0] * inv, o[i][1] * inv,
                               o[i][2] * inv, o[i][3] * inv);
        *(float4*)&O[base + (size_t)(n0 + ty * 4 + i) * DIMC + tx * 4] = v;
    }
}

// ---------------------------------------------------------------------------
// Final: gate = sigmoid(G); fused = vis*g + O*(1-g); out = LN(fused).
// One block per row.
// ---------------------------------------------------------------------------
__global__ __launch_bounds__(256)
void fuse_ln_kernel(const float* __restrict__ vis,
                    const float* __restrict__ Oc,
                    const float* __restrict__ G,
                    const float* __restrict__ w,
                    const float* __restrict__ b,
                    float* __restrict__ out)
{
    const int row = blockIdx.x;
    float f[3];
    float s = 0.f, q = 0.f;
    #pragma unroll
    for (int u = 0; u < 3; ++u) {
        const size_t idx = (size_t)row * DIMC + threadIdx.x + u * 256;
        const float vv = vis[idx];
        const float oo = Oc[idx];
        const float gg = 1.f / (1.f + __expf(-G[idx]));
        f[u] = vv * gg + oo * (1.f - gg);
        s += f[u];
        q += f[u] * f[u];
    }
    #pragma unroll
    for (int off = 32; off > 0; off >>= 1) {
        s += __shfl_down(s, off);
        q += __shfl_down(q, off);
    }
    __shared__ float ls[8];
    const int wid = threadIdx.x >> 6;
    if ((threadIdx.x & 63) == 0) { ls[wid] = s; ls[4 + wid] = q; }
    __syncthreads();
    if (threadIdx.x == 0) {
        ls[0] = ls[0] + ls[1] + ls[2] + ls[3];
        ls[4] = ls[4] + ls[5] + ls[6] + ls[7];
    }
    __syncthreads();
    const float mu  = ls[0] * (1.f / DIMC);
    const float var = ls[4] * (1.f / DIMC) - mu * mu;
    const float rs  = rsqrtf(var + EPSLN);
    #pragma unroll
    for (int u = 0; u < 3; ++u) {
        const int j = threadIdx.x + u * 256;
        out[(size_t)row * DIMC + j] = (f[u] - mu) * rs * w[j] + b[j];
    }
}

// ---------------------------------------------------------------------------
extern "C" void kernel_launch(void* const* d_in, const int* in_sizes, int n_in,
                              void* d_out, int out_size, void* d_ws, size_t ws_size,
                              hipStream_t stream)
{
    const float* vis  = (const float*)d_in[0];
    const float* inf  = (const float*)d_in[1];
    const float* wq   = (const float*)d_in[2];
    const float* bq   = (const float*)d_in[3];
    const float* lnqw = (const float*)d_in[4];
    const float* lnqb = (const float*)d_in[5];
    const float* wk   = (const float*)d_in[6];
    const float* bk   = (const float*)d_in[7];
    const float* lnkw = (const float*)d_in[8];
    const float* lnkb = (const float*)d_in[9];
    const float* wv   = (const float*)d_in[10];
    const float* bv   = (const float*)d_in[11];
    const float* lnvw = (const float*)d_in[12];
    const float* lnvb = (const float*)d_in[13];
    const float* pos  = (const float*)d_in[14];
    const float* wo   = (const float*)d_in[15];
    const float* bo   = (const float*)d_in[16];
    const float* gw   = (const float*)d_in[17];
    const float* gb   = (const float*)d_in[18];
    const float* lnw  = (const float*)d_in[19];
    const float* lnb  = (const float*)d_in[20];

    float* ws = (float*)d_ws;
    const size_t BUF = (size_t)NB * NSEQ * DIMC;   // 3,145,728 floats
    float* q  = ws;                 // Q after proj+LN
    float* kk = ws + BUF;           // scale*LN(K) + pos
    float* v  = ws + 2 * BUF;       // V after proj+LN
    float* ao = (float*)d_out;      // attention out (scratch; overwritten at end)
    float* Oc = q;                  // O-proj result, reuses q buffer
    float* G  = kk;                 // gate logits, reuses kk buffer

    dim3 blk(256);
    dim3 ggemm(64, 12);

    // Q/K/V projections + LN (K gets scale+pos folded in)
    gemm_bias_kernel<false><<<ggemm, blk, 0, stream>>>(inf, wq, bq, q, DIMC);
    ln_rows_kernel<0><<<dim3(4096), blk, 0, stream>>>(q, lnqw, lnqb, nullptr);
    gemm_bias_kernel<false><<<ggemm, blk, 0, stream>>>(vis, wk, bk, kk, DIMC);
    ln_rows_kernel<1><<<dim3(4096), blk, 0, stream>>>(kk, lnkw, lnkb, pos);
    gemm_bias_kernel<false><<<ggemm, blk, 0, stream>>>(vis, wv, bv, v, DIMC);
    ln_rows_kernel<0><<<dim3(4096), blk, 0, stream>>>(v, lnvw, lnvb, nullptr);

    // attention
    attn_kernel<<<dim3(NB * NH, NSEQ / 64), blk, 0, stream>>>(q, kk, v, ao);

    // output projection (q buffer is dead -> reuse as Oc)
    gemm_bias_kernel<false><<<ggemm, blk, 0, stream>>>(ao, wo, bo, Oc, DIMC);

    // gate logits: G = vis @ gw[:, :768]^T + gb ; G += Oc @ gw[:, 768:]^T
    gemm_bias_kernel<false><<<ggemm, blk, 0, stream>>>(vis, gw, gb, G, 2 * DIMC);
    gemm_bias_kernel<true ><<<ggemm, blk, 0, stream>>>(Oc, gw + DIMC, nullptr, G, 2 * DIMC);

    // fuse + final LN -> d_out
    fuse_ln_kernel<<<dim3(4096), blk, 0, stream>>>(vis, Oc, G, lnw, lnb, (float*)d_out);
}

// Round 2
// 335.743 us; speedup vs baseline: 3.1165x; 3.1165x over previous
//
#include <hip/hip_runtime.h>
#include <hip/hip_bf16.h>

#define DIMC 768
#define NSEQ 2048
#define NB 2
#define NH 12
#define HD 64
#define EPSLN 1e-5f

typedef __attribute__((ext_vector_type(8))) short     bf16x8;
typedef __attribute__((ext_vector_type(8))) unsigned short ushort8;
typedef __attribute__((ext_vector_type(4))) unsigned short ushort4v;
typedef __attribute__((ext_vector_type(4))) float     f32x4;

__device__ __forceinline__ unsigned short f2b(float f) {
    union { float f; unsigned u; } x; x.f = f;
    unsigned r = x.u + 0x7fffu + ((x.u >> 16) & 1u);   // RNE
    return (unsigned short)(r >> 16);
}

#define MFMA16(a, b, c) __builtin_amdgcn_mfma_f32_16x16x32_bf16((a), (b), (c), 0, 0, 0)

// ---------------------------------------------------------------------------
// One-shot f32 -> bf16 cast of all weights + both activations.
// Segments (in float4 groups): wq,wk,wv,wo (147456 ea), gw (294912),
// vis (786432), inf (786432). Total 2457600 groups -> grid 9600 x 256.
// ---------------------------------------------------------------------------
__global__ __launch_bounds__(256)
void cast_all_kernel(const float* __restrict__ wq, const float* __restrict__ wk,
                     const float* __restrict__ wv, const float* __restrict__ wo,
                     const float* __restrict__ gw, const float* __restrict__ vis,
                     const float* __restrict__ inf_,
                     unsigned short* __restrict__ o_wq, unsigned short* __restrict__ o_wk,
                     unsigned short* __restrict__ o_wv, unsigned short* __restrict__ o_wo,
                     unsigned short* __restrict__ o_gw, unsigned short* __restrict__ o_vis,
                     unsigned short* __restrict__ o_inf)
{
    const int g = blockIdx.x * 256 + threadIdx.x;
    const int W = 147456;           // 589824/4
    const float* src; unsigned short* dst; int off;
    if      (g < 1*W)            { src = wq;   dst = o_wq;  off = g;          }
    else if (g < 2*W)            { src = wk;   dst = o_wk;  off = g - 1*W;    }
    else if (g < 3*W)            { src = wv;   dst = o_wv;  off = g - 2*W;    }
    else if (g < 4*W)            { src = wo;   dst = o_wo;  off = g - 3*W;    }
    else if (g < 4*W + 294912)   { src = gw;   dst = o_gw;  off = g - 4*W;    }
    else if (g < 4*W + 1081344)  { src = vis;  dst = o_vis; off = g - 4*W - 294912; }
    else                         { src = inf_; dst = o_inf; off = g - 4*W - 1081344; }
    f32x4 v = ((const f32x4*)src)[off];
    ushort4v t;
    t[0] = f2b(v[0]); t[1] = f2b(v[1]); t[2] = f2b(v[2]); t[3] = f2b(v[3]);
    ((ushort4v*)dst)[off] = t;
}

// ---------------------------------------------------------------------------
// bf16 MFMA GEMM: C[4096][768] = A[4096][768] @ W^T (+bias) (+C if ACC).
// W rows stride ldw. 64x64 tile, 4 waves (2x2), wave tile 32x32 = 2x2 frags,
// BK=64. LDS [64][72] (pad 8 -> 2-way conflicts = free).
// WBF: also write bf16 copy of C.
// ---------------------------------------------------------------------------
template<int ACC, int WBF>
__global__ __launch_bounds__(256)
void gemm_bf16_kernel(const unsigned short* __restrict__ A,
                      const unsigned short* __restrict__ W,
                      const float* __restrict__ bias,
                      float* __restrict__ C,
                      unsigned short* __restrict__ Cb,
                      int ldw)
{
    __shared__ unsigned short As[64][72];
    __shared__ unsigned short Bs[64][72];
    const int m0 = blockIdx.x * 64, n0 = blockIdx.y * 64;
    const int lane = threadIdx.x & 63, wid = threadIdx.x >> 6;
    const int wm = wid >> 1, wn = wid & 1;
    const int r16 = lane & 15, kg = lane >> 4;

    f32x4 acc[2][2] = {};

    const int sr = threadIdx.x >> 2;          // 0..63
    const int sc = (threadIdx.x & 3) * 16;    // 0,16,32,48
    const size_t arow = (size_t)(m0 + sr) * DIMC;
    const size_t brow = (size_t)(n0 + sr) * (size_t)ldw;

    for (int k0 = 0; k0 < DIMC; k0 += 64) {
        // issue global loads early (hide under previous compute)
        ushort8 a0 = *(const ushort8*)&A[arow + k0 + sc];
        ushort8 a1 = *(const ushort8*)&A[arow + k0 + sc + 8];
        ushort8 b0 = *(const ushort8*)&W[brow + k0 + sc];
        ushort8 b1 = *(const ushort8*)&W[brow + k0 + sc + 8];
        if (k0) __syncthreads();              // prior reads of As/Bs done
        *(ushort8*)&As[sr][sc]     = a0;
        *(ushort8*)&As[sr][sc + 8] = a1;
        *(ushort8*)&Bs[sr][sc]     = b0;
        *(ushort8*)&Bs[sr][sc + 8] = b1;
        __syncthreads();
        #pragma unroll
        for (int ks = 0; ks < 2; ++ks) {
            bf16x8 af0 = *(const bf16x8*)&As[wm*32 +      r16][ks*32 + kg*8];
            bf16x8 af1 = *(const bf16x8*)&As[wm*32 + 16 + r16][ks*32 + kg*8];
            bf16x8 bg0 = *(const bf16x8*)&Bs[wn*32 +      r16][ks*32 + kg*8];
            bf16x8 bg1 = *(const bf16x8*)&Bs[wn*32 + 16 + r16][ks*32 + kg*8];
            acc[0][0] = MFMA16(af0, bg0, acc[0][0]);
            acc[0][1] = MFMA16(af0, bg1, acc[0][1]);
            acc[1][0] = MFMA16(af1, bg0, acc[1][0]);
            acc[1][1] = MFMA16(af1, bg1, acc[1][1]);
        }
    }

    #pragma unroll
    for (int mi = 0; mi < 2; ++mi)
    #pragma unroll
    for (int nj = 0; nj < 2; ++nj) {
        const int gr = m0 + wm*32 + mi*16 + kg*4;     // + r
        const int gc = n0 + wn*32 + nj*16 + r16;
        const float bv = bias ? bias[gc] : 0.f;
        #pragma unroll
        for (int r = 0; r < 4; ++r) {
            const size_t idx = (size_t)(gr + r) * DIMC + gc;
            float v = acc[mi][nj][r] + bv;
            if (ACC) v += C[idx];
            C[idx] = v;
            if (WBF) Cb[idx] = f2b(v);
        }
    }
}

// ---------------------------------------------------------------------------
// LayerNorm: reads f32, writes bf16. MODE 1: y = y*0.125 + pos (K-fold).
// ---------------------------------------------------------------------------
template<int MODE>
__global__ __launch_bounds__(256)
void ln_bf16_kernel(const float* __restrict__ Z,
                    const float* __restrict__ w,
                    const float* __restrict__ b,
                    const float* __restrict__ pos,
                    unsigned short* __restrict__ out)
{
    const int row = blockIdx.x;
    const int n = row & (NSEQ - 1);
    float x[3];
    float s = 0.f, q = 0.f;
    #pragma unroll
    for (int u = 0; u < 3; ++u) {
        const int j = threadIdx.x + u * 256;
        x[u] = Z[(size_t)row * DIMC + j];
        s += x[u];
        q += x[u] * x[u];
    }
    #pragma unroll
    for (int off = 32; off > 0; off >>= 1) {
        s += __shfl_down(s, off);
        q += __shfl_down(q, off);
    }
    __shared__ float ls[8];
    const int wv_ = threadIdx.x >> 6;
    if ((threadIdx.x & 63) == 0) { ls[wv_] = s; ls[4 + wv_] = q; }
    __syncthreads();
    if (threadIdx.x == 0) {
        ls[0] = ls[0] + ls[1] + ls[2] + ls[3];
        ls[4] = ls[4] + ls[5] + ls[6] + ls[7];
    }
    __syncthreads();
    const float mu  = ls[0] * (1.f / DIMC);
    const float var = ls[4] * (1.f / DIMC) - mu * mu;
    const float rs  = rsqrtf(var + EPSLN);
    #pragma unroll
    for (int u = 0; u < 3; ++u) {
        const int j = threadIdx.x + u * 256;
        float y = (x[u] - mu) * rs * w[j] + b[j];
        if (MODE == 1) y = y * 0.125f + pos[(size_t)n * DIMC + j];
        out[(size_t)row * DIMC + j] = f2b(y);
    }
}

// ---------------------------------------------------------------------------
// bf16 MFMA flash attention. K already = 0.125*LN(k)+pos.
// Grid (24, 32); 4 waves; wave owns 16 q-rows. KV tile = 64.
// Q in registers; K row-major LDS (B-frag contiguous); V transposed LDS;
// P transposed through per-wave LDS slab (wave-local, no barrier).
// O written in place over Q (block reads only its own q rows).
// ---------------------------------------------------------------------------
__global__ __launch_bounds__(256)
void attn_bf16_kernel(const unsigned short* __restrict__ Q,
                      const unsigned short* __restrict__ K,
                      const unsigned short* __restrict__ V,
                      unsigned short* __restrict__ O)
{
    __shared__ unsigned short Ks[64][72];
    __shared__ unsigned short Vt[64][72];
    __shared__ unsigned short Ps[4][16][72];

    const int bh = blockIdx.x;
    const int b = bh / NH, h = bh % NH;
    const int n0 = blockIdx.y * 64;
    const int lane = threadIdx.x & 63, w = threadIdx.x >> 6;
    const int r16 = lane & 15, kg = lane >> 4;

    const size_t base = (size_t)b * NSEQ * DIMC + (size_t)h * HD;

    // Q fragments in registers (rows n0 + w*16 + r16, k = d)
    const size_t qoff = base + (size_t)(n0 + w * 16 + r16) * DIMC + kg * 8;
    bf16x8 aq0 = *(const bf16x8*)&Q[qoff];
    bf16x8 aq1 = *(const bf16x8*)&Q[qoff + 32];

    f32x4 o[4] = {};
    float mrow[4] = {-1e30f, -1e30f, -1e30f, -1e30f};
    float lrow[4] = {};

    for (int m0 = 0; m0 < NSEQ; m0 += 64) {
        __syncthreads();
        {   // stage K tile row-major: 4 threads per row, 16 cols each
            const int kv = threadIdx.x >> 2;
            const int c  = (threadIdx.x & 3) * 16;
            const size_t go = base + (size_t)(m0 + kv) * DIMC + c;
            *(ushort8*)&Ks[kv][c]     = *(const ushort8*)&K[go];
            *(ushort8*)&Ks[kv][c + 8] = *(const ushort8*)&K[go + 8];
        }
        {   // stage V transposed: Vt[d][kv]
            const int kv = threadIdx.x & 63;
            const int dg = (threadIdx.x >> 6) * 16;
            const size_t go = base + (size_t)(m0 + kv) * DIMC + dg;
            #pragma unroll
            for (int i = 0; i < 4; ++i) {
                ushort4v v4 = *(const ushort4v*)&V[go + i * 4];
                Vt[dg + i*4 + 0][kv] = v4[0];
                Vt[dg + i*4 + 1][kv] = v4[1];
                Vt[dg + i*4 + 2][kv] = v4[2];
                Vt[dg + i*4 + 3][kv] = v4[3];
            }
        }
        __syncthreads();

        // S = Q @ K^T : 4 col-frags, k = 64 (2 mfma each)
        f32x4 sv[4] = {};
        #pragma unroll
        for (int nj = 0; nj < 4; ++nj) {
            bf16x8 kb0 = *(const bf16x8*)&Ks[nj*16 + r16][kg*8];
            bf16x8 kb1 = *(const bf16x8*)&Ks[nj*16 + r16][32 + kg*8];
            sv[nj] = MFMA16(aq0, kb0, sv[nj]);
            sv[nj] = MFMA16(aq1, kb1, sv[nj]);
        }

        // online softmax; row q = (lane>>4)*4 + r lives in the 16 lanes with
        // equal lane>>4, spread over lane&15 (cols). xor 1,2,4,8 stays in group.
        #pragma unroll
        for (int r = 0; r < 4; ++r) {
            float mx = fmaxf(fmaxf(sv[0][r], sv[1][r]), fmaxf(sv[2][r], sv[3][r]));
            #pragma unroll
            for (int off = 1; off < 16; off <<= 1)
                mx = fmaxf(mx, __shfl_xor(mx, off));
            const float mnew = fmaxf(mrow[r], mx);
            const float corr = __expf(mrow[r] - mnew);
            float ps = 0.f;
            #pragma unroll
            for (int nj = 0; nj < 4; ++nj) {
                const float p = __expf(sv[nj][r] - mnew);
                sv[nj][r] = p;
                ps += p;
            }
            #pragma unroll
            for (int off = 1; off < 16; off <<= 1)
                ps += __shfl_xor(ps, off);
            lrow[r] = lrow[r] * corr + ps;
            mrow[r] = mnew;
            o[0][r] *= corr; o[1][r] *= corr; o[2][r] *= corr; o[3][r] *= corr;
            // P -> per-wave LDS slab, transposed to A-layout [q][kv]
            const int qr = kg * 4 + r;
            #pragma unroll
            for (int nj = 0; nj < 4; ++nj)
                Ps[w][qr][nj*16 + r16] = f2b(sv[nj][r]);
        }

        // O += P @ V  (A = P from slab, B = Vt; wave-local slab, no barrier)
        bf16x8 pa0 = *(const bf16x8*)&Ps[w][r16][kg*8];
        bf16x8 pa1 = *(const bf16x8*)&Ps[w][r16][32 + kg*8];
        #pragma unroll
        for (int nj = 0; nj < 4; ++nj) {
            bf16x8 vb0 = *(const bf16x8*)&Vt[nj*16 + r16][kg*8];
            bf16x8 vb1 = *(const bf16x8*)&Vt[nj*16 + r16][32 + kg*8];
            o[nj] = MFMA16(pa0, vb0, o[nj]);
            o[nj] = MFMA16(pa1, vb1, o[nj]);
        }
    }

    // epilogue: O row q = (lane>>4)*4 + r, col d = nj*16 + r16
    float inv[4];
    #pragma unroll
    for (int r = 0; r < 4; ++r) inv[r] = 1.f / lrow[r];
    #pragma unroll
    for (int nj = 0; nj < 4; ++nj)
    #pragma unroll
    for (int r = 0; r < 4; ++r) {
        const size_t go = base + (size_t)(n0 + w*16 + kg*4 + r) * DIMC + nj*16 + r16;
        O[go] = f2b(o[nj][r] * inv[r]);
    }
}

// ---------------------------------------------------------------------------
// gate = sigmoid(G); fused = vis*g + Oc*(1-g); out = LN(fused). f32.
// G aliases d_out; every element is read before written by the same thread.
// ---------------------------------------------------------------------------
__global__ __launch_bounds__(256)
void fuse_ln_kernel(const float* __restrict__ vis,
                    const float* __restrict__ Oc,
                    const float* __restrict__ G,
                    const float* __restrict__ w,
                    const float* __restrict__ b,
                    float* __restrict__ out)
{
    const int row = blockIdx.x;
    float f[3];
    float s = 0.f, q = 0.f;
    #pragma unroll
    for (int u = 0; u < 3; ++u) {
        const size_t idx = (size_t)row * DIMC + threadIdx.x + u * 256;
        const float vv = vis[idx];
        const float oo = Oc[idx];
        const float gg = 1.f / (1.f + __expf(-G[idx]));
        f[u] = vv * gg + oo * (1.f - gg);
        s += f[u];
        q += f[u] * f[u];
    }
    #pragma unroll
    for (int off = 32; off > 0; off >>= 1) {
        s += __shfl_down(s, off);
        q += __shfl_down(q, off);
    }
    __shared__ float ls[8];
    const int wv_ = threadIdx.x >> 6;
    if ((threadIdx.x & 63) == 0) { ls[wv_] = s; ls[4 + wv_] = q; }
    __syncthreads();
    if (threadIdx.x == 0) {
        ls[0] = ls[0] + ls[1] + ls[2] + ls[3];
        ls[4] = ls[4] + ls[5] + ls[6] + ls[7];
    }
    __syncthreads();
    const float mu  = ls[0] * (1.f / DIMC);
    const float var = ls[4] * (1.f / DIMC) - mu * mu;
    const float rs  = rsqrtf(var + EPSLN);
    #pragma unroll
    for (int u = 0; u < 3; ++u) {
        const int j = threadIdx.x + u * 256;
        out[(size_t)row * DIMC + j] = (f[u] - mu) * rs * w[j] + b[j];
    }
}

// ---------------------------------------------------------------------------
extern "C" void kernel_launch(void* const* d_in, const int* in_sizes, int n_in,
                              void* d_out, int out_size, void* d_ws, size_t ws_size,
                              hipStream_t stream)
{
    const float* vis  = (const float*)d_in[0];
    const float* inf_ = (const float*)d_in[1];
    const float* wq   = (const float*)d_in[2];
    const float* bq   = (const float*)d_in[3];
    const float* lnqw = (const float*)d_in[4];
    const float* lnqb = (const float*)d_in[5];
    const float* wk   = (const float*)d_in[6];
    const float* bk   = (const float*)d_in[7];
    const float* lnkw = (const float*)d_in[8];
    const float* lnkb = (const float*)d_in[9];
    const float* wv   = (const float*)d_in[10];
    const float* bv   = (const float*)d_in[11];
    const float* lnvw = (const float*)d_in[12];
    const float* lnvb = (const float*)d_in[13];
    const float* pos  = (const float*)d_in[14];
    const float* wo   = (const float*)d_in[15];
    const float* bo   = (const float*)d_in[16];
    const float* gw   = (const float*)d_in[17];
    const float* gb   = (const float*)d_in[18];
    const float* lnw  = (const float*)d_in[19];
    const float* lnb  = (const float*)d_in[20];

    const size_t WEL = 589824;            // 768*768
    const size_t GEL = 1179648;           // 768*1536
    const size_t BUF = (size_t)NB * NSEQ * DIMC;   // 3145728

    unsigned short* p = (unsigned short*)d_ws;
    unsigned short* wq_b  = p;  p += WEL;
    unsigned short* wk_b  = p;  p += WEL;
    unsigned short* wv_b  = p;  p += WEL;
    unsigned short* wo_b  = p;  p += WEL;
    unsigned short* gw_b  = p;  p += GEL;
    unsigned short* vis_b = p;  p += BUF;
    unsigned short* inf_b = p;  p += BUF;
    unsigned short* q_b   = p;  p += BUF;   // also attention output (in place)
    unsigned short* k_b   = p;  p += BUF;
    unsigned short* v_b   = p;  p += BUF;
    unsigned short* oc_b  = p;  p += BUF;
    float* Oc  = (float*)k_b;               // f32, aliases k_b+v_b (dead then)
    float* tmp = (float*)d_out;             // f32 GEMM scratch / gate logits
    float* G   = (float*)d_out;

    dim3 blk(256);
    dim3 ggemm(64, 12);

    cast_all_kernel<<<dim3(9600), blk, 0, stream>>>(
        wq, wk, wv, wo, gw, vis, inf_,
        wq_b, wk_b, wv_b, wo_b, gw_b, vis_b, inf_b);

    // Q/K/V projections + LN (K folds 0.125*LN + pos)
    gemm_bf16_kernel<0,0><<<ggemm, blk, 0, stream>>>(inf_b, wq_b, bq, tmp, nullptr, DIMC);
    ln_bf16_kernel<0><<<dim3(4096), blk, 0, stream>>>(tmp, lnqw, lnqb, nullptr, q_b);
    gemm_bf16_kernel<0,0><<<ggemm, blk, 0, stream>>>(vis_b, wk_b, bk, tmp, nullptr, DIMC);
    ln_bf16_kernel<1><<<dim3(4096), blk, 0, stream>>>(tmp, lnkw, lnkb, pos, k_b);
    gemm_bf16_kernel<0,0><<<ggemm, blk, 0, stream>>>(vis_b, wv_b, bv, tmp, nullptr, DIMC);
    ln_bf16_kernel<0><<<dim3(4096), blk, 0, stream>>>(tmp, lnvw, lnvb, nullptr, v_b);

    // attention (O overwrites q_b in place)
    attn_bf16_kernel<<<dim3(NB * NH, NSEQ / 64), blk, 0, stream>>>(q_b, k_b, v_b, q_b);

    // output projection -> Oc f32 (aliases dead k/v) + bf16 copy
    gemm_bf16_kernel<0,1><<<ggemm, blk, 0, stream>>>(q_b, wo_b, bo, Oc, oc_b, DIMC);

    // gate logits G = vis@gw1^T + gb ; G += Oc@gw2^T
    gemm_bf16_kernel<0,0><<<ggemm, blk, 0, stream>>>(vis_b, gw_b, gb, G, nullptr, 2 * DIMC);
    gemm_bf16_kernel<1,0><<<ggemm, blk, 0, stream>>>(oc_b, gw_b + DIMC, nullptr, G, nullptr, 2 * DIMC);

    // fuse + final LN -> d_out
    fuse_ln_kernel<<<dim3(4096), blk, 0, stream>>>(vis, Oc, G, lnw, lnb, (float*)d_out);
}

// Round 3
// 326.124 us; speedup vs baseline: 3.2084x; 1.0295x over previous
//
#include <hip/hip_runtime.h>
#include <hip/hip_bf16.h>

#define DIMC 768
#define NSEQ 2048
#define NB 2
#define NH 12
#define HD 64
#define EPSLN 1e-5f
#define LOG2E 1.44269504f

typedef __attribute__((ext_vector_type(8))) short          bf16x8;
typedef __attribute__((ext_vector_type(8))) unsigned short ushort8;
typedef __attribute__((ext_vector_type(4))) unsigned short ushort4v;
typedef __attribute__((ext_vector_type(4))) float          f32x4;
typedef unsigned int u32;

__device__ __forceinline__ unsigned short f2b(float f) {
    union { float f; unsigned u; } x; x.f = f;
    unsigned r = x.u + 0x7fffu + ((x.u >> 16) & 1u);   // RNE
    return (unsigned short)(r >> 16);
}
__device__ __forceinline__ float b2f(unsigned short v) {
    union { unsigned u; float f; } x; x.u = ((u32)v) << 16; return x.f;
}

#define MFMA16(a, b, c) __builtin_amdgcn_mfma_f32_16x16x32_bf16((a), (b), (c), 0, 0, 0)

__device__ __forceinline__ void gl_lds16(const unsigned short* g, unsigned short* l) {
    __builtin_amdgcn_global_load_lds(
        (const __attribute__((address_space(1))) u32*)(const void*)g,
        (__attribute__((address_space(3))) u32*)(void*)l, 16, 0, 0);
}

// ---------------------------------------------------------------------------
// Cast pass: f32 -> bf16 for weights+activations; builds merged KVG weight
// [2304][768] = [wk ; wv ; gw[:, :768]], g2w [768][768] = gw[:, 768:],
// and concatenated f32 bias [bk|bv|gb] (2304).
// Indexing in float4 groups.
// ---------------------------------------------------------------------------
#define G_WQ   147456
#define G_MW   442368
#define G_G2   147456
#define G_WO   147456
#define G_VIS  786432
#define G_INF  786432
#define G_BF_TOTAL (G_WQ + G_MW + G_G2 + G_WO + G_VIS + G_INF)   // 2457600
#define G_BIAS 576
#define G_ALL  (G_BF_TOTAL + G_BIAS)                              // 2458176

__global__ __launch_bounds__(256)
void cast_all_kernel(const float* __restrict__ wq, const float* __restrict__ wk,
                     const float* __restrict__ wv, const float* __restrict__ gw,
                     const float* __restrict__ wo,
                     const float* __restrict__ bk, const float* __restrict__ bv,
                     const float* __restrict__ gb,
                     const float* __restrict__ vis, const float* __restrict__ inf_,
                     unsigned short* __restrict__ o_wq, unsigned short* __restrict__ o_mw,
                     unsigned short* __restrict__ o_g2, unsigned short* __restrict__ o_wo,
                     unsigned short* __restrict__ o_vis, unsigned short* __restrict__ o_inf,
                     float* __restrict__ o_biasc)
{
    const int g = blockIdx.x * 256 + threadIdx.x;
    if (g >= G_ALL) return;
    if (g >= G_BF_TOTAL) {            // bias concat, f32 out
        const int e0 = (g - G_BF_TOTAL) * 4;
        float4 r;
        float* pr = (float*)&r;
        #pragma unroll
        for (int t = 0; t < 4; ++t) {
            const int e = e0 + t;
            pr[t] = (e < 768) ? bk[e] : (e < 1536) ? bv[e - 768] : gb[e - 1536];
        }
        *(float4*)&o_biasc[e0] = r;
        return;
    }
    const float* src; unsigned short* dst; int soff, doff = 0;
    int gg = g;
    if (gg < G_WQ) { src = wq; dst = o_wq; soff = gg; doff = gg; }
    else if ((gg -= G_WQ) < G_MW) {
        const int row = gg / 192, c4 = gg % 192;
        dst = o_mw; doff = gg;
        if      (row < 768)  { src = wk; soff = row * 192 + c4; }
        else if (row < 1536) { src = wv; soff = (row - 768) * 192 + c4; }
        else                 { src = gw; soff = (row - 1536) * 384 + c4; }
    }
    else if ((gg -= G_MW) < G_G2) {
        const int row = gg / 192, c4 = gg % 192;
        src = gw; soff = row * 384 + 192 + c4; dst = o_g2; doff = gg;
    }
    else if ((gg -= G_G2) < G_WO)  { src = wo;   dst = o_wo;  soff = gg; doff = gg; }
    else if ((gg -= G_WO) < G_VIS) { src = vis;  dst = o_vis; soff = gg; doff = gg; }
    else { gg -= G_VIS;              src = inf_; dst = o_inf; soff = gg; doff = gg; }
    f32x4 v = ((const f32x4*)src)[soff];
    ushort4v t;
    t[0] = f2b(v[0]); t[1] = f2b(v[1]); t[2] = f2b(v[2]); t[3] = f2b(v[3]);
    ((ushort4v*)dst)[doff] = t;
}

// ---------------------------------------------------------------------------
// m97-style bf16 MFMA GEMM: 128x128 tile, BK=64, 4 waves (2x2), 4x4 frags,
// linear LDS staged via global_load_lds width 16.
// MODE 0: Cf f32 = A@W^T + bias                     [Q proj]
// MODE 1: cols<1536 -> Cb bf16 (ld 1536); cols>=1536 -> Cf f32 (ld 768)  [KVG]
// MODE 2: Cf f32 + Cb bf16 (both ld 768) + bias     [wo proj]
// MODE 3: Cf f32 += A@W^T (no bias)                 [gate2 ACC]
// ---------------------------------------------------------------------------
template<int MODE>
__global__ __launch_bounds__(256)
void gemm128(const unsigned short* __restrict__ A,
             const unsigned short* __restrict__ W,
             const float* __restrict__ bias,
             float* __restrict__ Cf,
             unsigned short* __restrict__ Cb)
{
    __shared__ unsigned short As[128 * 64];
    __shared__ unsigned short Bs[128 * 64];
    const int m0 = blockIdx.x * 128, n0 = blockIdx.y * 128;
    const int lane = threadIdx.x & 63, wid = threadIdx.x >> 6;
    const int wm = wid >> 1, wn = wid & 1;
    const int r16 = lane & 15, kg = lane >> 4;
    const int lrow = lane >> 3;          // 0..7
    const int lcol = (lane & 7) * 8;     // elem offset within 64-col tile

    f32x4 acc[4][4] = {};

    for (int k0 = 0; k0 < DIMC; k0 += 64) {
        if (k0) __syncthreads();
        #pragma unroll
        for (int i = 0; i < 4; ++i) {
            const int c = wid * 4 + i;           // 1KB chunk id
            const int row = c * 8 + lrow;
            gl_lds16(&A[(size_t)(m0 + row) * DIMC + k0 + lcol], &As[c * 512]);
            gl_lds16(&W[(size_t)(n0 + row) * DIMC + k0 + lcol], &Bs[c * 512]);
        }
        __syncthreads();
        #pragma unroll
        for (int ks = 0; ks < 2; ++ks) {
            bf16x8 af[4], bg[4];
            #pragma unroll
            for (int mi = 0; mi < 4; ++mi)
                af[mi] = *(const bf16x8*)&As[(wm * 64 + mi * 16 + r16) * 64 + ks * 32 + kg * 8];
            #pragma unroll
            for (int nj = 0; nj < 4; ++nj)
                bg[nj] = *(const bf16x8*)&Bs[(wn * 64 + nj * 16 + r16) * 64 + ks * 32 + kg * 8];
            __builtin_amdgcn_s_setprio(1);
            #pragma unroll
            for (int mi = 0; mi < 4; ++mi)
                #pragma unroll
                for (int nj = 0; nj < 4; ++nj)
                    acc[mi][nj] = MFMA16(af[mi], bg[nj], acc[mi][nj]);
            __builtin_amdgcn_s_setprio(0);
        }
    }

    #pragma unroll
    for (int mi = 0; mi < 4; ++mi)
    #pragma unroll
    for (int nj = 0; nj < 4; ++nj) {
        const int gr = m0 + wm * 64 + mi * 16 + kg * 4;
        const int gc = n0 + wn * 64 + nj * 16 + r16;
        const float bvl = (MODE == 3) ? 0.f : bias[gc];
        #pragma unroll
        for (int r = 0; r < 4; ++r) {
            const float val = acc[mi][nj][r] + bvl;
            if (MODE == 0) {
                Cf[(size_t)(gr + r) * DIMC + gc] = val;
            } else if (MODE == 1) {
                if (gc < 1536) Cb[(size_t)(gr + r) * 1536 + gc] = f2b(val);
                else           Cf[(size_t)(gr + r) * DIMC + (gc - 1536)] = val;
            } else if (MODE == 2) {
                const size_t idx = (size_t)(gr + r) * DIMC + gc;
                Cf[idx] = val;
                Cb[idx] = f2b(val);
            } else {
                const size_t idx = (size_t)(gr + r) * DIMC + gc;
                Cf[idx] += val;
            }
        }
    }
}

// ---------------------------------------------------------------------------
// LayerNorm -> bf16. INBF: input bf16 (stride ld) else f32 (stride ld).
// MODE 1: y = y*(0.125*LOG2E) + pos*LOG2E  (K-fold: attn scale + pos + log2e)
// ---------------------------------------------------------------------------
template<int INBF, int MODE>
__global__ __launch_bounds__(256)
void ln_bf16_kernel(const void* __restrict__ Zv,
                    int ld,
                    const float* __restrict__ w,
                    const float* __restrict__ b,
                    const float* __restrict__ pos,
                    unsigned short* __restrict__ out)
{
    const int row = blockIdx.x;
    const int n = row & (NSEQ - 1);
    float x[3];
    float s = 0.f, q = 0.f;
    #pragma unroll
    for (int u = 0; u < 3; ++u) {
        const int j = threadIdx.x + u * 256;
        if (INBF) x[u] = b2f(((const unsigned short*)Zv)[(size_t)row * ld + j]);
        else      x[u] = ((const float*)Zv)[(size_t)row * ld + j];
        s += x[u];
        q += x[u] * x[u];
    }
    #pragma unroll
    for (int off = 32; off > 0; off >>= 1) {
        s += __shfl_down(s, off);
        q += __shfl_down(q, off);
    }
    __shared__ float ls[8];
    const int wv_ = threadIdx.x >> 6;
    if ((threadIdx.x & 63) == 0) { ls[wv_] = s; ls[4 + wv_] = q; }
    __syncthreads();
    if (threadIdx.x == 0) {
        ls[0] = ls[0] + ls[1] + ls[2] + ls[3];
        ls[4] = ls[4] + ls[5] + ls[6] + ls[7];
    }
    __syncthreads();
    const float mu  = ls[0] * (1.f / DIMC);
    const float var = ls[4] * (1.f / DIMC) - mu * mu;
    const float rs  = rsqrtf(var + EPSLN);
    #pragma unroll
    for (int u = 0; u < 3; ++u) {
        const int j = threadIdx.x + u * 256;
        float y = (x[u] - mu) * rs * w[j] + b[j];
        if (MODE == 1) y = y * (0.125f * LOG2E) + pos[(size_t)n * DIMC + j] * LOG2E;
        out[(size_t)row * DIMC + j] = f2b(y);
    }
}

// ---------------------------------------------------------------------------
// Swapped-QK^T bf16 MFMA flash attention. K holds log2e*(0.125*LN(k)+pos),
// so S is in log2 domain and exp2f is exact. S^T = mfma(K,Q): each lane owns
// one q-column (q = lane&15) -> in-register row softmax (15 ops + 2 shfl).
// P packed via v_cvt_pk_bf16_f32 into per-wave LDS slab; PV = mfma(P, Vt).
// ---------------------------------------------------------------------------
__global__ __launch_bounds__(256)
void attn_bf16_kernel(const unsigned short* __restrict__ Q,
                      const unsigned short* __restrict__ K,
                      const unsigned short* __restrict__ V,
                      unsigned short* __restrict__ O)
{
    __shared__ unsigned short Ks[64][72];
    __shared__ unsigned short Vt[64][72];
    __shared__ unsigned short Ps[4][16][72];

    const int bh = blockIdx.x;
    const int b = bh / NH, h = bh % NH;
    const int n0 = blockIdx.y * 64;
    const int lane = threadIdx.x & 63, w = threadIdx.x >> 6;
    const int r16 = lane & 15, kg = lane >> 4;

    const size_t base = (size_t)b * NSEQ * DIMC + (size_t)h * HD;

    // Q fragments (B-operand: col = q = r16, k = d)
    const size_t qoff = base + (size_t)(n0 + w * 16 + r16) * DIMC + kg * 8;
    bf16x8 aq0 = *(const bf16x8*)&Q[qoff];
    bf16x8 aq1 = *(const bf16x8*)&Q[qoff + 32];

    f32x4 o[4] = {};
    float m_run = -1e30f, l_run = 0.f;

    for (int m0 = 0; m0 < NSEQ; m0 += 64) {
        __syncthreads();
        {   // stage K tile row-major
            const int kv = threadIdx.x >> 2;
            const int c  = (threadIdx.x & 3) * 16;
            const size_t go = base + (size_t)(m0 + kv) * DIMC + c;
            *(ushort8*)&Ks[kv][c]     = *(const ushort8*)&K[go];
            *(ushort8*)&Ks[kv][c + 8] = *(const ushort8*)&K[go + 8];
        }
        {   // stage V transposed: Vt[d][kv]
            const int kv = threadIdx.x & 63;
            const int dg = (threadIdx.x >> 6) * 16;
            const size_t go = base + (size_t)(m0 + kv) * DIMC + dg;
            #pragma unroll
            for (int i = 0; i < 4; ++i) {
                ushort4v v4 = *(const ushort4v*)&V[go + i * 4];
                Vt[dg + i * 4 + 0][kv] = v4[0];
                Vt[dg + i * 4 + 1][kv] = v4[1];
                Vt[dg + i * 4 + 2][kv] = v4[2];
                Vt[dg + i * 4 + 3][kv] = v4[3];
            }
        }
        __syncthreads();

        // S^T = mfma(A=K, B=Q); lane: q = r16, kv = 16f + kg*4 + j
        f32x4 sv[4];
        #pragma unroll
        for (int f = 0; f < 4; ++f) sv[f] = (f32x4){0.f, 0.f, 0.f, 0.f};
        __builtin_amdgcn_s_setprio(1);
        #pragma unroll
        for (int f = 0; f < 4; ++f) {
            bf16x8 kb0 = *(const bf16x8*)&Ks[f * 16 + r16][kg * 8];
            bf16x8 kb1 = *(const bf16x8*)&Ks[f * 16 + r16][32 + kg * 8];
            sv[f] = MFMA16(kb0, aq0, sv[f]);
            sv[f] = MFMA16(kb1, aq1, sv[f]);
        }
        __builtin_amdgcn_s_setprio(0);

        // in-register softmax for column q = r16 (log2 domain)
        float mt = sv[0][0];
        #pragma unroll
        for (int f = 0; f < 4; ++f)
            #pragma unroll
            for (int j = 0; j < 4; ++j)
                mt = fmaxf(mt, sv[f][j]);
        mt = fmaxf(mt, __shfl_xor(mt, 16));
        mt = fmaxf(mt, __shfl_xor(mt, 32));
        const float mnew = fmaxf(m_run, mt);
        const float corr = exp2f(m_run - mnew);
        float p[4][4];
        float st = 0.f;
        #pragma unroll
        for (int f = 0; f < 4; ++f)
            #pragma unroll
            for (int j = 0; j < 4; ++j) {
                p[f][j] = exp2f(sv[f][j] - mnew);
                st += p[f][j];
            }
        st += __shfl_xor(st, 16);
        st += __shfl_xor(st, 32);
        l_run = l_run * corr + st;
        m_run = mnew;

        // pack P -> Ps[w][q][kv] (pairs along j are kv-consecutive)
        #pragma unroll
        for (int f = 0; f < 4; ++f) {
            u32 w0, w1;
            asm("v_cvt_pk_bf16_f32 %0, %1, %2" : "=v"(w0) : "v"(p[f][0]), "v"(p[f][1]));
            asm("v_cvt_pk_bf16_f32 %0, %1, %2" : "=v"(w1) : "v"(p[f][2]), "v"(p[f][3]));
            *(u32*)&Ps[w][r16][kg * 4 + 16 * f]     = w0;
            *(u32*)&Ps[w][r16][kg * 4 + 2 + 16 * f] = w1;
        }

        // rescale O (O-layout rows q' = kg*4+jj; fetch corr via bpermute)
        #pragma unroll
        for (int jj = 0; jj < 4; ++jj) {
            const float cq = __shfl(corr, kg * 4 + jj);
            o[0][jj] *= cq; o[1][jj] *= cq; o[2][jj] *= cq; o[3][jj] *= cq;
        }

        // O += P @ V (A = P rows q, B = Vt cols d; wave-local slab, DS in-order)
        bf16x8 pa0 = *(const bf16x8*)&Ps[w][r16][kg * 8];
        bf16x8 pa1 = *(const bf16x8*)&Ps[w][r16][32 + kg * 8];
        __builtin_amdgcn_s_setprio(1);
        #pragma unroll
        for (int nj = 0; nj < 4; ++nj) {
            bf16x8 vb0 = *(const bf16x8*)&Vt[nj * 16 + r16][kg * 8];
            bf16x8 vb1 = *(const bf16x8*)&Vt[nj * 16 + r16][32 + kg * 8];
            o[nj] = MFMA16(pa0, vb0, o[nj]);
            o[nj] = MFMA16(pa1, vb1, o[nj]);
        }
        __builtin_amdgcn_s_setprio(0);
    }

    float linv[4];
    #pragma unroll
    for (int jj = 0; jj < 4; ++jj)
        linv[jj] = 1.f / __shfl(l_run, kg * 4 + jj);
    #pragma unroll
    for (int nj = 0; nj < 4; ++nj)
    #pragma unroll
    for (int jj = 0; jj < 4; ++jj) {
        const size_t go = base + (size_t)(n0 + w * 16 + kg * 4 + jj) * DIMC + nj * 16 + r16;
        O[go] = f2b(o[nj][jj] * linv[jj]);
    }
}

// ---------------------------------------------------------------------------
// gate = sigmoid(G); fused = vis*g + Oc*(1-g); out = LN(fused). f32.
// G aliases d_out; each thread reads its G elements before writing out.
// ---------------------------------------------------------------------------
__global__ __launch_bounds__(256)
void fuse_ln_kernel(const float* __restrict__ vis,
                    const float* __restrict__ Oc,
                    const float* __restrict__ G,
                    const float* __restrict__ w,
                    const float* __restrict__ b,
                    float* __restrict__ out)
{
    const int row = blockIdx.x;
    float f[3];
    float s = 0.f, q = 0.f;
    #pragma unroll
    for (int u = 0; u < 3; ++u) {
        const size_t idx = (size_t)row * DIMC + threadIdx.x + u * 256;
        const float vv = vis[idx];
        const float oo = Oc[idx];
        const float gg = 1.f / (1.f + __expf(-G[idx]));
        f[u] = vv * gg + oo * (1.f - gg);
        s += f[u];
        q += f[u] * f[u];
    }
    #pragma unroll
    for (int off = 32; off > 0; off >>= 1) {
        s += __shfl_down(s, off);
        q += __shfl_down(q, off);
    }
    __shared__ float ls[8];
    const int wv_ = threadIdx.x >> 6;
    if ((threadIdx.x & 63) == 0) { ls[wv_] = s; ls[4 + wv_] = q; }
    __syncthreads();
    if (threadIdx.x == 0) {
        ls[0] = ls[0] + ls[1] + ls[2] + ls[3];
        ls[4] = ls[4] + ls[5] + ls[6] + ls[7];
    }
    __syncthreads();
    const float mu  = ls[0] * (1.f / DIMC);
    const float var = ls[4] * (1.f / DIMC) - mu * mu;
    const float rs  = rsqrtf(var + EPSLN);
    #pragma unroll
    for (int u = 0; u < 3; ++u) {
        const int j = threadIdx.x + u * 256;
        out[(size_t)row * DIMC + j] = (f[u] - mu) * rs * w[j] + b[j];
    }
}

// ---------------------------------------------------------------------------
extern "C" void kernel_launch(void* const* d_in, const int* in_sizes, int n_in,
                              void* d_out, int out_size, void* d_ws, size_t ws_size,
                              hipStream_t stream)
{
    const float* vis  = (const float*)d_in[0];
    const float* inf_ = (const float*)d_in[1];
    const float* wq   = (const float*)d_in[2];
    const float* bq   = (const float*)d_in[3];
    const float* lnqw = (const float*)d_in[4];
    const float* lnqb = (const float*)d_in[5];
    const float* wk   = (const float*)d_in[6];
    const float* bk   = (const float*)d_in[7];
    const float* lnkw = (const float*)d_in[8];
    const float* lnkb = (const float*)d_in[9];
    const float* wv   = (const float*)d_in[10];
    const float* bv   = (const float*)d_in[11];
    const float* lnvw = (const float*)d_in[12];
    const float* lnvb = (const float*)d_in[13];
    const float* pos  = (const float*)d_in[14];
    const float* wo   = (const float*)d_in[15];
    const float* bo   = (const float*)d_in[16];
    const float* gw   = (const float*)d_in[17];
    const float* gb   = (const float*)d_in[18];
    const float* lnw  = (const float*)d_in[19];
    const float* lnb  = (const float*)d_in[20];

    const size_t WEL = 589824;                    // 768*768
    const size_t MWEL = 1769472;                  // 2304*768
    const size_t BUF = (size_t)NB * NSEQ * DIMC;  // 3145728

    unsigned short* p = (unsigned short*)d_ws;
    unsigned short* wq_b  = p;  p += WEL;
    unsigned short* mw_b  = p;  p += MWEL;   // [wk;wv;gw1]
    unsigned short* g2_b  = p;  p += WEL;    // gw2
    unsigned short* wo_b  = p;  p += WEL;
    unsigned short* vis_b = p;  p += BUF;
    unsigned short* inf_b = p;  p += BUF;
    unsigned short* q_b   = p;  p += BUF;    // post-LN Q; attn O in place
    unsigned short* k_b   = p;  p += BUF;
    unsigned short* v_b   = p;  p += BUF;
    unsigned short* kvpre = p;  p += 2 * BUF;  // [4096][1536] pre-LN K|V
    float* biasc = (float*)p;                   // 2304 f32

    float* Gd  = (float*)d_out;     // Q-pre scratch, then gate logits
    float* Oc  = (float*)k_b;       // f32, aliases k_b+v_b (dead after attn)
    unsigned short* oc_b = inf_b;   // bf16 Oc, aliases inf_b (dead after Q GEMM)

    dim3 blk(256);

    cast_all_kernel<<<dim3((G_ALL + 255) / 256), blk, 0, stream>>>(
        wq, wk, wv, gw, wo, bk, bv, gb, vis, inf_,
        wq_b, mw_b, g2_b, wo_b, vis_b, inf_b, biasc);

    // Q projection + LN
    gemm128<0><<<dim3(32, 6), blk, 0, stream>>>(inf_b, wq_b, bq, Gd, nullptr);
    ln_bf16_kernel<0, 0><<<dim3(4096), blk, 0, stream>>>(Gd, DIMC, lnqw, lnqb, nullptr, q_b);

    // K|V|gate1 merged projection
    gemm128<1><<<dim3(32, 18), blk, 0, stream>>>(vis_b, mw_b, biasc, Gd, kvpre);
    ln_bf16_kernel<1, 1><<<dim3(4096), blk, 0, stream>>>(kvpre, 1536, lnkw, lnkb, pos, k_b);
    ln_bf16_kernel<1, 0><<<dim3(4096), blk, 0, stream>>>(kvpre + DIMC, 1536, lnvw, lnvb, nullptr, v_b);

    // attention (O overwrites q_b in place)
    attn_bf16_kernel<<<dim3(NB * NH, NSEQ / 64), blk, 0, stream>>>(q_b, k_b, v_b, q_b);

    // output projection -> Oc f32 + bf16 copy
    gemm128<2><<<dim3(32, 6), blk, 0, stream>>>(q_b, wo_b, bo, Oc, oc_b);

    // gate logits: G += Oc @ gw2^T
    gemm128<3><<<dim3(32, 6), blk, 0, stream>>>(oc_b, g2_b, nullptr, Gd, nullptr);

    // fuse + final LN -> d_out
    fuse_ln_kernel<<<dim3(4096), blk, 0, stream>>>(vis, Oc, Gd, lnw, lnb, (float*)d_out);
}

// Round 4
// 313.957 us; speedup vs baseline: 3.3328x; 1.0388x over previous
//
#include <hip/hip_runtime.h>
#include <hip/hip_bf16.h>

#define DIMC 768
#define NSEQ 2048
#define NB 2
#define NH 12
#define HD 64
#define EPSLN 1e-5f
#define LOG2E 1.44269504f

typedef __attribute__((ext_vector_type(8))) short          bf16x8;
typedef __attribute__((ext_vector_type(8))) unsigned short ushort8;
typedef __attribute__((ext_vector_type(4))) unsigned short ushort4v;
typedef __attribute__((ext_vector_type(4))) float          f32x4;
typedef unsigned int u32;

__device__ __forceinline__ unsigned short f2b(float f) {
    union { float f; unsigned u; } x; x.f = f;
    unsigned r = x.u + 0x7fffu + ((x.u >> 16) & 1u);   // RNE
    return (unsigned short)(r >> 16);
}
__device__ __forceinline__ float b2f(unsigned short v) {
    union { unsigned u; float f; } x; x.u = ((u32)v) << 16; return x.f;
}

#define MFMA16(a, b, c) __builtin_amdgcn_mfma_f32_16x16x32_bf16((a), (b), (c), 0, 0, 0)

__device__ __forceinline__ void gl_lds16(const unsigned short* g, unsigned short* l) {
    __builtin_amdgcn_global_load_lds(
        (const __attribute__((address_space(1))) u32*)(const void*)g,
        (__attribute__((address_space(3))) u32*)(void*)l, 16, 0, 0);
}

// ---------------------------------------------------------------------------
// Cast pass (unchanged from R3): f32 -> bf16; merged KVG weight
// [2304][768] = [wk ; wv ; gw[:, :768]], g2w = gw[:, 768:], bias concat.
// ---------------------------------------------------------------------------
#define G_WQ   147456
#define G_MW   442368
#define G_G2   147456
#define G_WO   147456
#define G_VIS  786432
#define G_INF  786432
#define G_BF_TOTAL (G_WQ + G_MW + G_G2 + G_WO + G_VIS + G_INF)   // 2457600
#define G_BIAS 576
#define G_ALL  (G_BF_TOTAL + G_BIAS)                              // 2458176

__global__ __launch_bounds__(256)
void cast_all_kernel(const float* __restrict__ wq, const float* __restrict__ wk,
                     const float* __restrict__ wv, const float* __restrict__ gw,
                     const float* __restrict__ wo,
                     const float* __restrict__ bk, const float* __restrict__ bv,
                     const float* __restrict__ gb,
                     const float* __restrict__ vis, const float* __restrict__ inf_,
                     unsigned short* __restrict__ o_wq, unsigned short* __restrict__ o_mw,
                     unsigned short* __restrict__ o_g2, unsigned short* __restrict__ o_wo,
                     unsigned short* __restrict__ o_vis, unsigned short* __restrict__ o_inf,
                     float* __restrict__ o_biasc)
{
    const int g = blockIdx.x * 256 + threadIdx.x;
    if (g >= G_ALL) return;
    if (g >= G_BF_TOTAL) {
        const int e0 = (g - G_BF_TOTAL) * 4;
        float4 r;
        float* pr = (float*)&r;
        #pragma unroll
        for (int t = 0; t < 4; ++t) {
            const int e = e0 + t;
            pr[t] = (e < 768) ? bk[e] : (e < 1536) ? bv[e - 768] : gb[e - 1536];
        }
        *(float4*)&o_biasc[e0] = r;
        return;
    }
    const float* src; unsigned short* dst; int soff, doff = 0;
    int gg = g;
    if (gg < G_WQ) { src = wq; dst = o_wq; soff = gg; doff = gg; }
    else if ((gg -= G_WQ) < G_MW) {
        const int row = gg / 192, c4 = gg % 192;
        dst = o_mw; doff = gg;
        if      (row < 768)  { src = wk; soff = row * 192 + c4; }
        else if (row < 1536) { src = wv; soff = (row - 768) * 192 + c4; }
        else                 { src = gw; soff = (row - 1536) * 384 + c4; }
    }
    else if ((gg -= G_MW) < G_G2) {
        const int row = gg / 192, c4 = gg % 192;
        src = gw; soff = row * 384 + 192 + c4; dst = o_g2; doff = gg;
    }
    else if ((gg -= G_G2) < G_WO)  { src = wo;   dst = o_wo;  soff = gg; doff = gg; }
    else if ((gg -= G_WO) < G_VIS) { src = vis;  dst = o_vis; soff = gg; doff = gg; }
    else { gg -= G_VIS;              src = inf_; dst = o_inf; soff = gg; doff = gg; }
    f32x4 v = ((const f32x4*)src)[soff];
    ushort4v t;
    t[0] = f2b(v[0]); t[1] = f2b(v[1]); t[2] = f2b(v[2]); t[3] = f2b(v[3]);
    ((ushort4v*)dst)[doff] = t;
}

// ---------------------------------------------------------------------------
// bf16 MFMA GEMM: 128x64 tile, BK=64, 4 waves (2x2), wave tile 64x32.
// Explicit LDS double-buffer + counted vmcnt(6) (loads never drain mid-loop).
// MODE 0: Cf = A@W^T + bias            MODE 1: KVG split (bf16 ld1536 / f32)
// MODE 2: Cf + Cb bf16                 MODE 3: Cf += A@W^T
// ---------------------------------------------------------------------------
template<int MODE>
__global__ __launch_bounds__(256)
void gemm128x64(const unsigned short* __restrict__ A,
                const unsigned short* __restrict__ W,
                const float* __restrict__ bias,
                float* __restrict__ Cf,
                unsigned short* __restrict__ Cb)
{
    __shared__ unsigned short As[2][128 * 64];
    __shared__ unsigned short Bs[2][64 * 64];
    const int m0 = blockIdx.x * 128, n0 = blockIdx.y * 64;
    const int lane = threadIdx.x & 63, wid = threadIdx.x >> 6;
    const int wm = wid >> 1, wn = wid & 1;
    const int r16 = lane & 15, kg = lane >> 4;
    const int lr = lane >> 3, lc = (lane & 7) * 8;

    f32x4 acc[4][2] = {};

    auto stage = [&](int k0, int buf) {
        #pragma unroll
        for (int i = 0; i < 4; ++i) {
            const int c = wid * 4 + i;
            gl_lds16(&A[(size_t)(m0 + c * 8 + lr) * DIMC + k0 + lc], &As[buf][c * 512]);
        }
        #pragma unroll
        for (int i = 0; i < 2; ++i) {
            const int c = wid * 2 + i;
            gl_lds16(&W[(size_t)(n0 + c * 8 + lr) * DIMC + k0 + lc], &Bs[buf][c * 512]);
        }
    };

    stage(0, 0);
    for (int t = 0; t < 12; ++t) {
        const int cur = t & 1;
        if (t < 11) {
            stage((t + 1) * 64, cur ^ 1);
            asm volatile("s_waitcnt vmcnt(6)" ::: "memory");
        } else {
            asm volatile("s_waitcnt vmcnt(0)" ::: "memory");
        }
        __builtin_amdgcn_s_barrier();
        __builtin_amdgcn_sched_barrier(0);
        #pragma unroll
        for (int ks = 0; ks < 2; ++ks) {
            bf16x8 af[4], bg[2];
            #pragma unroll
            for (int mi = 0; mi < 4; ++mi)
                af[mi] = *(const bf16x8*)&As[cur][(wm * 64 + mi * 16 + r16) * 64 + ks * 32 + kg * 8];
            #pragma unroll
            for (int nj = 0; nj < 2; ++nj)
                bg[nj] = *(const bf16x8*)&Bs[cur][(wn * 32 + nj * 16 + r16) * 64 + ks * 32 + kg * 8];
            __builtin_amdgcn_s_setprio(1);
            #pragma unroll
            for (int mi = 0; mi < 4; ++mi)
                #pragma unroll
                for (int nj = 0; nj < 2; ++nj)
                    acc[mi][nj] = MFMA16(af[mi], bg[nj], acc[mi][nj]);
            __builtin_amdgcn_s_setprio(0);
        }
        __builtin_amdgcn_sched_barrier(0);
        __builtin_amdgcn_s_barrier();
    }

    #pragma unroll
    for (int mi = 0; mi < 4; ++mi)
    #pragma unroll
    for (int nj = 0; nj < 2; ++nj) {
        const int gr = m0 + wm * 64 + mi * 16 + kg * 4;
        const int gc = n0 + wn * 32 + nj * 16 + r16;
        const float bvl = (MODE == 3) ? 0.f : bias[gc];
        #pragma unroll
        for (int r = 0; r < 4; ++r) {
            const float val = acc[mi][nj][r] + bvl;
            if (MODE == 0) {
                Cf[(size_t)(gr + r) * DIMC + gc] = val;
            } else if (MODE == 1) {
                if (gc < 1536) Cb[(size_t)(gr + r) * 1536 + gc] = f2b(val);
                else           Cf[(size_t)(gr + r) * DIMC + (gc - 1536)] = val;
            } else if (MODE == 2) {
                const size_t idx = (size_t)(gr + r) * DIMC + gc;
                Cf[idx] = val;
                Cb[idx] = f2b(val);
            } else {
                const size_t idx = (size_t)(gr + r) * DIMC + gc;
                Cf[idx] += val;
            }
        }
    }
}

// ---------------------------------------------------------------------------
// LayerNorm -> bf16 (unchanged). MODE 1: y*(0.125*log2e) + pos*log2e.
// ---------------------------------------------------------------------------
template<int INBF, int MODE>
__global__ __launch_bounds__(256)
void ln_bf16_kernel(const void* __restrict__ Zv,
                    int ld,
                    const float* __restrict__ w,
                    const float* __restrict__ b,
                    const float* __restrict__ pos,
                    unsigned short* __restrict__ out)
{
    const int row = blockIdx.x;
    const int n = row & (NSEQ - 1);
    float x[3];
    float s = 0.f, q = 0.f;
    #pragma unroll
    for (int u = 0; u < 3; ++u) {
        const int j = threadIdx.x + u * 256;
        if (INBF) x[u] = b2f(((const unsigned short*)Zv)[(size_t)row * ld + j]);
        else      x[u] = ((const float*)Zv)[(size_t)row * ld + j];
        s += x[u];
        q += x[u] * x[u];
    }
    #pragma unroll
    for (int off = 32; off > 0; off >>= 1) {
        s += __shfl_down(s, off);
        q += __shfl_down(q, off);
    }
    __shared__ float ls[8];
    const int wv_ = threadIdx.x >> 6;
    if ((threadIdx.x & 63) == 0) { ls[wv_] = s; ls[4 + wv_] = q; }
    __syncthreads();
    if (threadIdx.x == 0) {
        ls[0] = ls[0] + ls[1] + ls[2] + ls[3];
        ls[4] = ls[4] + ls[5] + ls[6] + ls[7];
    }
    __syncthreads();
    const float mu  = ls[0] * (1.f / DIMC);
    const float var = ls[4] * (1.f / DIMC) - mu * mu;
    const float rs  = rsqrtf(var + EPSLN);
    #pragma unroll
    for (int u = 0; u < 3; ++u) {
        const int j = threadIdx.x + u * 256;
        float y = (x[u] - mu) * rs * w[j] + b[j];
        if (MODE == 1) y = y * (0.125f * LOG2E) + pos[(size_t)n * DIMC + j] * LOG2E;
        out[(size_t)row * DIMC + j] = f2b(y);
    }
}

// ---------------------------------------------------------------------------
// Swapped-QK^T flash attention v2: wave-Q=32 (block 128 q-rows), KVBLK=64,
// register prefetch of next K/V tile (issued a full tile early), defer-max.
// Grid (24, 16), 256 threads.
// ---------------------------------------------------------------------------
__global__ __launch_bounds__(256)
void attn_bf16_kernel(const unsigned short* __restrict__ Q,
                      const unsigned short* __restrict__ K,
                      const unsigned short* __restrict__ V,
                      unsigned short* __restrict__ O)
{
    __shared__ unsigned short Ks[64][72];
    __shared__ unsigned short Vt[64][72];
    __shared__ unsigned short Ps[4][32][72];

    const int bh = blockIdx.x;
    const int b = bh / NH, h = bh % NH;
    const int n0 = blockIdx.y * 128;
    const int lane = threadIdx.x & 63, w = threadIdx.x >> 6;
    const int r16 = lane & 15, kg = lane >> 4;

    const size_t base = (size_t)b * NSEQ * DIMC + (size_t)h * HD;

    // Q fragments (B-operand): aq[qf][ks], col q = qf*16+r16, k = d
    bf16x8 aq[2][2];
    #pragma unroll
    for (int qf = 0; qf < 2; ++qf) {
        const size_t qo = base + (size_t)(n0 + w * 32 + qf * 16 + r16) * DIMC + kg * 8;
        aq[qf][0] = *(const bf16x8*)&Q[qo];
        aq[qf][1] = *(const bf16x8*)&Q[qo + 32];
    }

    // staging source pointers (tile 0)
    const int krow = threadIdx.x >> 2;
    const int kcol = (threadIdx.x & 3) * 16;
    const unsigned short* Kg = K + base + (size_t)krow * DIMC + kcol;
    const int vrow = threadIdx.x & 63;
    const int vcol = (threadIdx.x >> 6) * 16;
    const unsigned short* Vg = V + base + (size_t)vrow * DIMC + vcol;

    f32x4 o[2][4] = {};
    float m_run[2] = {-1e30f, -1e30f};
    float l_run[2] = {0.f, 0.f};

    // prologue: stage tile 0
    ushort8  kr0 = *(const ushort8*)Kg;
    ushort8  kr1 = *(const ushort8*)(Kg + 8);
    ushort4v vr[4];
    #pragma unroll
    for (int i = 0; i < 4; ++i) vr[i] = *(const ushort4v*)(Vg + i * 4);
    *(ushort8*)&Ks[krow][kcol]     = kr0;
    *(ushort8*)&Ks[krow][kcol + 8] = kr1;
    #pragma unroll
    for (int i = 0; i < 4; ++i)
        #pragma unroll
        for (int e = 0; e < 4; ++e)
            Vt[vcol + i * 4 + e][vrow] = vr[i][e];
    __syncthreads();

    for (int m0 = 0; m0 < NSEQ; m0 += 64) {
        const bool more = (m0 + 64 < NSEQ);
        if (more) {   // prefetch next K/V tile into registers (full tile early)
            const size_t adv = (size_t)(m0 + 64) * DIMC;
            kr0 = *(const ushort8*)(Kg + adv);
            kr1 = *(const ushort8*)(Kg + adv + 8);
            #pragma unroll
            for (int i = 0; i < 4; ++i) vr[i] = *(const ushort4v*)(Vg + adv + i * 4);
        }
        __builtin_amdgcn_sched_barrier(0);   // pin prefetch issue before compute

        // S^T = mfma(A=K, B=Q): sv[f][qf], lane q = qf*16+r16, kv = f*16+kg*4+j
        f32x4 sv[4][2];
        #pragma unroll
        for (int f = 0; f < 4; ++f)
            #pragma unroll
            for (int qf = 0; qf < 2; ++qf)
                sv[f][qf] = (f32x4){0.f, 0.f, 0.f, 0.f};
        __builtin_amdgcn_s_setprio(1);
        #pragma unroll
        for (int f = 0; f < 4; ++f) {
            bf16x8 kb0 = *(const bf16x8*)&Ks[f * 16 + r16][kg * 8];
            bf16x8 kb1 = *(const bf16x8*)&Ks[f * 16 + r16][32 + kg * 8];
            #pragma unroll
            for (int qf = 0; qf < 2; ++qf) {
                sv[f][qf] = MFMA16(kb0, aq[qf][0], sv[f][qf]);
                sv[f][qf] = MFMA16(kb1, aq[qf][1], sv[f][qf]);
            }
        }
        __builtin_amdgcn_s_setprio(0);

        // per-column max (log2 domain)
        float mt[2];
        #pragma unroll
        for (int qf = 0; qf < 2; ++qf) {
            float m = sv[0][qf][0];
            #pragma unroll
            for (int f = 0; f < 4; ++f)
                #pragma unroll
                for (int j = 0; j < 4; ++j)
                    m = fmaxf(m, sv[f][qf][j]);
            m = fmaxf(m, __shfl_xor(m, 16));
            m = fmaxf(m, __shfl_xor(m, 32));
            mt[qf] = m;
        }
        const float growth = fmaxf(mt[0] - m_run[0], mt[1] - m_run[1]);
        const bool defer = __all(growth <= 8.0f);
        float corr[2] = {1.f, 1.f};
        if (!defer) {
            #pragma unroll
            for (int qf = 0; qf < 2; ++qf) {
                const float mn = fmaxf(m_run[qf], mt[qf]);
                corr[qf] = exp2f(m_run[qf] - mn);
                m_run[qf] = mn;
            }
        }

        // p = exp2(s - m), pack to Ps, column sums
        #pragma unroll
        for (int qf = 0; qf < 2; ++qf) {
            float st = 0.f;
            #pragma unroll
            for (int f = 0; f < 4; ++f) {
                float p0 = exp2f(sv[f][qf][0] - m_run[qf]);
                float p1 = exp2f(sv[f][qf][1] - m_run[qf]);
                float p2 = exp2f(sv[f][qf][2] - m_run[qf]);
                float p3 = exp2f(sv[f][qf][3] - m_run[qf]);
                st += (p0 + p1) + (p2 + p3);
                u32 w0, w1;
                asm("v_cvt_pk_bf16_f32 %0, %1, %2" : "=v"(w0) : "v"(p0), "v"(p1));
                asm("v_cvt_pk_bf16_f32 %0, %1, %2" : "=v"(w1) : "v"(p2), "v"(p3));
                *(u32*)&Ps[w][qf * 16 + r16][f * 16 + kg * 4]     = w0;
                *(u32*)&Ps[w][qf * 16 + r16][f * 16 + kg * 4 + 2] = w1;
            }
            st += __shfl_xor(st, 16);
            st += __shfl_xor(st, 32);
            l_run[qf] = l_run[qf] * corr[qf] + st;
        }

        // O rescale (skipped on deferred tiles)
        if (!defer) {
            #pragma unroll
            for (int ri = 0; ri < 2; ++ri)
                #pragma unroll
                for (int jj = 0; jj < 4; ++jj) {
                    const float cq = __shfl(corr[ri], kg * 4 + jj);
                    #pragma unroll
                    for (int nj = 0; nj < 4; ++nj) o[ri][nj][jj] *= cq;
                }
        }

        // O += P @ V  (A = P rows q, B = Vt cols d; wave-local slab)
        __builtin_amdgcn_s_setprio(1);
        #pragma unroll
        for (int ri = 0; ri < 2; ++ri) {
            bf16x8 pa0 = *(const bf16x8*)&Ps[w][ri * 16 + r16][kg * 8];
            bf16x8 pa1 = *(const bf16x8*)&Ps[w][ri * 16 + r16][32 + kg * 8];
            #pragma unroll
            for (int nj = 0; nj < 4; ++nj) {
                bf16x8 vb0 = *(const bf16x8*)&Vt[nj * 16 + r16][kg * 8];
                bf16x8 vb1 = *(const bf16x8*)&Vt[nj * 16 + r16][32 + kg * 8];
                o[ri][nj] = MFMA16(pa0, vb0, o[ri][nj]);
                o[ri][nj] = MFMA16(pa1, vb1, o[ri][nj]);
            }
        }
        __builtin_amdgcn_s_setprio(0);

        // all waves done reading Ks/Vt -> overwrite with prefetched tile
        __builtin_amdgcn_s_barrier();
        __builtin_amdgcn_sched_barrier(0);
        if (more) {
            *(ushort8*)&Ks[krow][kcol]     = kr0;
            *(ushort8*)&Ks[krow][kcol + 8] = kr1;
            #pragma unroll
            for (int i = 0; i < 4; ++i)
                #pragma unroll
                for (int e = 0; e < 4; ++e)
                    Vt[vcol + i * 4 + e][vrow] = vr[i][e];
        }
        __syncthreads();
    }

    // epilogue: row q = ri*16 + kg*4 + jj, col d = nj*16 + r16
    float rinv[2];
    rinv[0] = 1.f / l_run[0];
    rinv[1] = 1.f / l_run[1];
    #pragma unroll
    for (int ri = 0; ri < 2; ++ri)
        #pragma unroll
        for (int jj = 0; jj < 4; ++jj) {
            const float cq = __shfl(rinv[ri], kg * 4 + jj);
            #pragma unroll
            for (int nj = 0; nj < 4; ++nj) {
                const size_t go = base + (size_t)(n0 + w * 32 + ri * 16 + kg * 4 + jj) * DIMC
                                + nj * 16 + r16;
                O[go] = f2b(o[ri][nj][jj] * cq);
            }
        }
}

// ---------------------------------------------------------------------------
// gate = sigmoid(G); fused = vis*g + Oc*(1-g); out = LN(fused). (unchanged)
// ---------------------------------------------------------------------------
__global__ __launch_bounds__(256)
void fuse_ln_kernel(const float* __restrict__ vis,
                    const float* __restrict__ Oc,
                    const float* __restrict__ G,
                    const float* __restrict__ w,
                    const float* __restrict__ b,
                    float* __restrict__ out)
{
    const int row = blockIdx.x;
    float f[3];
    float s = 0.f, q = 0.f;
    #pragma unroll
    for (int u = 0; u < 3; ++u) {
        const size_t idx = (size_t)row * DIMC + threadIdx.x + u * 256;
        const float vv = vis[idx];
        const float oo = Oc[idx];
        const float gg = 1.f / (1.f + __expf(-G[idx]));
        f[u] = vv * gg + oo * (1.f - gg);
        s += f[u];
        q += f[u] * f[u];
    }
    #pragma unroll
    for (int off = 32; off > 0; off >>= 1) {
        s += __shfl_down(s, off);
        q += __shfl_down(q, off);
    }
    __shared__ float ls[8];
    const int wv_ = threadIdx.x >> 6;
    if ((threadIdx.x & 63) == 0) { ls[wv_] = s; ls[4 + wv_] = q; }
    __syncthreads();
    if (threadIdx.x == 0) {
        ls[0] = ls[0] + ls[1] + ls[2] + ls[3];
        ls[4] = ls[4] + ls[5] + ls[6] + ls[7];
    }
    __syncthreads();
    const float mu  = ls[0] * (1.f / DIMC);
    const float var = ls[4] * (1.f / DIMC) - mu * mu;
    const float rs  = rsqrtf(var + EPSLN);
    #pragma unroll
    for (int u = 0; u < 3; ++u) {
        const int j = threadIdx.x + u * 256;
        out[(size_t)row * DIMC + j] = (f[u] - mu) * rs * w[j] + b[j];
    }
}

// ---------------------------------------------------------------------------
extern "C" void kernel_launch(void* const* d_in, const int* in_sizes, int n_in,
                              void* d_out, int out_size, void* d_ws, size_t ws_size,
                              hipStream_t stream)
{
    const float* vis  = (const float*)d_in[0];
    const float* inf_ = (const float*)d_in[1];
    const float* wq   = (const float*)d_in[2];
    const float* bq   = (const float*)d_in[3];
    const float* lnqw = (const float*)d_in[4];
    const float* lnqb = (const float*)d_in[5];
    const float* wk   = (const float*)d_in[6];
    const float* bk   = (const float*)d_in[7];
    const float* lnkw = (const float*)d_in[8];
    const float* lnkb = (const float*)d_in[9];
    const float* wv   = (const float*)d_in[10];
    const float* bv   = (const float*)d_in[11];
    const float* lnvw = (const float*)d_in[12];
    const float* lnvb = (const float*)d_in[13];
    const float* pos  = (const float*)d_in[14];
    const float* wo   = (const float*)d_in[15];
    const float* bo   = (const float*)d_in[16];
    const float* gw   = (const float*)d_in[17];
    const float* gb   = (const float*)d_in[18];
    const float* lnw  = (const float*)d_in[19];
    const float* lnb  = (const float*)d_in[20];

    const size_t WEL = 589824;                    // 768*768
    const size_t MWEL = 1769472;                  // 2304*768
    const size_t BUF = (size_t)NB * NSEQ * DIMC;  // 3145728

    unsigned short* p = (unsigned short*)d_ws;
    unsigned short* wq_b  = p;  p += WEL;
    unsigned short* mw_b  = p;  p += MWEL;   // [wk;wv;gw1]
    unsigned short* g2_b  = p;  p += WEL;    // gw2
    unsigned short* wo_b  = p;  p += WEL;
    unsigned short* vis_b = p;  p += BUF;
    unsigned short* inf_b = p;  p += BUF;
    unsigned short* q_b   = p;  p += BUF;    // post-LN Q; attn O in place
    unsigned short* k_b   = p;  p += BUF;
    unsigned short* v_b   = p;  p += BUF;
    unsigned short* kvpre = p;  p += 2 * BUF;  // [4096][1536] pre-LN K|V
    float* biasc = (float*)p;                   // 2304 f32

    float* Gd  = (float*)d_out;     // Q-pre scratch, then gate logits
    float* Oc  = (float*)k_b;       // f32, aliases k_b+v_b (dead after attn)
    unsigned short* oc_b = inf_b;   // bf16 Oc, aliases inf_b (dead after Q GEMM)

    dim3 blk(256);

    cast_all_kernel<<<dim3((G_ALL + 255) / 256), blk, 0, stream>>>(
        wq, wk, wv, gw, wo, bk, bv, gb, vis, inf_,
        wq_b, mw_b, g2_b, wo_b, vis_b, inf_b, biasc);

    // Q projection + LN
    gemm128x64<0><<<dim3(32, 12), blk, 0, stream>>>(inf_b, wq_b, bq, Gd, nullptr);
    ln_bf16_kernel<0, 0><<<dim3(4096), blk, 0, stream>>>(Gd, DIMC, lnqw, lnqb, nullptr, q_b);

    // K|V|gate1 merged projection
    gemm128x64<1><<<dim3(32, 36), blk, 0, stream>>>(vis_b, mw_b, biasc, Gd, kvpre);
    ln_bf16_kernel<1, 1><<<dim3(4096), blk, 0, stream>>>(kvpre, 1536, lnkw, lnkb, pos, k_b);
    ln_bf16_kernel<1, 0><<<dim3(4096), blk, 0, stream>>>(kvpre + DIMC, 1536, lnvw, lnvb, nullptr, v_b);

    // attention (O overwrites q_b in place)
    attn_bf16_kernel<<<dim3(NB * NH, NSEQ / 128), blk, 0, stream>>>(q_b, k_b, v_b, q_b);

    // output projection -> Oc f32 + bf16 copy
    gemm128x64<2><<<dim3(32, 12), blk, 0, stream>>>(q_b, wo_b, bo, Oc, oc_b);

    // gate logits: G += Oc @ gw2^T
    gemm128x64<3><<<dim3(32, 12), blk, 0, stream>>>(oc_b, g2_b, nullptr, Gd, nullptr);

    // fuse + final LN -> d_out
    fuse_ln_kernel<<<dim3(4096), blk, 0, stream>>>(vis, Oc, Gd, lnw, lnb, (float*)d_out);
}